// Round 9
// baseline (50.382 us; speedup 1.0000x reference)
//
#include <hip/hip_runtime.h>

typedef float f32x4 __attribute__((ext_vector_type(4)));

#define MDIM 8192
#define NDIM 8192
#define KDIM 64

#define BM 16
#define BN 256
#define WROW 68   // wave-private LDS row stride in dwords (16 x 68 x 4B = 4.25 KB/wave)

// Swizzled fp8 fragment layout (unchanged): per 16-row(col) tile, 1024 B =
// [ks:2][g:4][r:16][8 B]; fragment load for lane (r,g): 8 B at tile*1024 +
// ks*512 + g*128 + r*8 -> 512 B contiguous per wave.

__device__ __forceinline__ int pk4(float a, float b, float c, float d) {
    int r = __builtin_amdgcn_cvt_pk_fp8_f32(a, b, 0, false);
    return __builtin_amdgcn_cvt_pk_fp8_f32(c, d, r, true);
}

// ---- fused quantize: blocks [0,128) -> q path, [128,256) -> k path ----
__global__ __launch_bounds__(256) void quant_both(const float* __restrict__ q,
                                                  const float* __restrict__ k,
                                                  int2* __restrict__ q8s,
                                                  int2* __restrict__ k8s) {
    const int bid = blockIdx.x;
    if (bid < 128) {
        int t = bid * 256 + threadIdx.x;                 // row m = t>>2, quarter qq = t&3
        const float4* p = reinterpret_cast<const float4*>(q) + (size_t)t * 4;
        float4 v0 = p[0], v1 = p[1], v2 = p[2], v3 = p[3];
        int p0 = pk4(v0.x, v0.y, v0.z, v0.w);
        int p1 = pk4(v1.x, v1.y, v1.z, v1.w);
        int p2 = pk4(v2.x, v2.y, v2.z, v2.w);
        int p3 = pk4(v3.x, v3.y, v3.z, v3.w);
        int m = t >> 2, qq = t & 3;
        int tile = m >> 4, r = m & 15, ks = qq >> 1, gb = (qq & 1) * 2;
        size_t base = (size_t)tile * 128 + ks * 64 + gb * 16 + r;  // int2 units
        q8s[base]      = make_int2(p0, p1);
        q8s[base + 16] = make_int2(p2, p3);
    } else {
        int bb = bid - 128;
        int qq = bb & 3;
        int n  = (bb >> 2) * 256 + threadIdx.x;          // column 0..8191
        int pk[4];
#pragma unroll
        for (int j = 0; j < 4; ++j) {
            int row = qq * 16 + j * 4;
            float v0 = k[(size_t)(row + 0) * NDIM + n];
            float v1 = k[(size_t)(row + 1) * NDIM + n];
            float v2 = k[(size_t)(row + 2) * NDIM + n];
            float v3 = k[(size_t)(row + 3) * NDIM + n];
            pk[j] = pk4(v0, v1, v2, v3);
        }
        int tile = n >> 4, r = n & 15, ks = qq >> 1, gb = (qq & 1) * 2;
        size_t base = (size_t)tile * 128 + ks * 64 + gb * 16 + r;
        k8s[base]      = make_int2(pk[0], pk[1]);
        k8s[base + 16] = make_int2(pk[2], pk[3]);
    }
}

// -------- persistent GEMM: barrier-free, vmcnt-wait-free store stream ------
// 1024 blocks (4/CU, co-resident). Block b owns rows [16*(b>>1), +16),
// cols [(b&1)*4096, +4096) = 16 panels of 256. A-frags loaded once.
// B-frags double-buffered in registers (prefetch panel i+1 during panel i).
// Epilogue is R8's wave-private LDS transpose: only lgkmcnt waits — stores
// stay in flight across panels, store queue is the only throttle.
__global__ __launch_bounds__(256, 4) void gemm_fp8(const long* __restrict__ A8,
                                                   const long* __restrict__ B8,
                                                   float* __restrict__ C) {
    __shared__ float lds[4 * BM * WROW];   // 17408 B

    const int w    = threadIdx.x >> 6;
    const int lane = threadIdx.x & 63;
    const int r    = lane & 15;
    const int g    = lane >> 4;
    const int fs   = g * 16 + r;          // fragment slot (long units)

    const int b    = blockIdx.x;          // 0..1023
    const int by   = b >> 1;              // band 0..511
    const int half = b & 1;
    const int rowbase = by * BM;
    const int colhalf = half * 4096;

    long a[2];
#pragma unroll
    for (int ks = 0; ks < 2; ++ks)
        a[ks] = A8[(size_t)by * 128 + ks * 64 + fs];

    float* wl = &lds[w * BM * WROW];

    long b0[8], b1[8];

#define LOADB(i, dst)                                                          \
    {                                                                          \
        const int colbase = colhalf + (i) * BN;                                \
        _Pragma("unroll") for (int n = 0; n < 4; ++n)                          \
            _Pragma("unroll") for (int ks = 0; ks < 2; ++ks)                   \
                dst[n * 2 + ks] =                                              \
                    B8[(size_t)((colbase >> 4) + w * 4 + n) * 128 + ks * 64 + fs]; \
    }

#define COMPSTORE(i, bb)                                                       \
    {                                                                          \
        const int colbase = colhalf + (i) * BN;                                \
        f32x4 acc[4] = {};                                                     \
        _Pragma("unroll") for (int n = 0; n < 4; ++n) {                        \
            acc[n] = __builtin_amdgcn_mfma_f32_16x16x32_fp8_fp8(               \
                a[0], bb[n * 2 + 0], acc[n], 0, 0, 0);                         \
            acc[n] = __builtin_amdgcn_mfma_f32_16x16x32_fp8_fp8(               \
                a[1], bb[n * 2 + 1], acc[n], 0, 0, 0);                         \
        }                                                                      \
        _Pragma("unroll") for (int n = 0; n < 4; ++n)                          \
            _Pragma("unroll") for (int j = 0; j < 4; ++j)                      \
                wl[(g * 4 + j) * WROW + n * 16 + r] = acc[n][j];               \
        __builtin_amdgcn_sched_barrier(0);                                     \
        asm volatile("s_waitcnt lgkmcnt(0)" ::: "memory");                     \
        __builtin_amdgcn_sched_barrier(0);                                     \
        _Pragma("unroll") for (int p = 0; p < 4; ++p) {                        \
            const int row = p * 4 + g;                                         \
            f32x4 v = *reinterpret_cast<const f32x4*>(&wl[row * WROW + 4 * r]); \
            *reinterpret_cast<f32x4*>(                                         \
                &C[(size_t)(rowbase + row) * NDIM + colbase + w * 64 + 4 * r]) = v; \
        }                                                                      \
    }

    LOADB(0, b0);
    for (int ii = 0; ii < 16; ii += 2) {
        LOADB(ii + 1, b1);
        COMPSTORE(ii, b0);
        const int inx = (ii + 2) & 15;    // wraps to 0 on last iter (harmless)
        LOADB(inx, b0);
        COMPSTORE(ii + 1, b1);
    }
#undef LOADB
#undef COMPSTORE
}

extern "C" void kernel_launch(void* const* d_in, const int* in_sizes, int n_in,
                              void* d_out, int out_size, void* d_ws, size_t ws_size,
                              hipStream_t stream) {
    const float* q = (const float*)d_in[0];   // [8192][64] fp32
    const float* k = (const float*)d_in[1];   // [64][8192] fp32
    float* C = (float*)d_out;                 // [8192][8192] fp32

    long* q8s = (long*)d_ws;                                  // 512 KB swizzled A
    long* k8s = q8s + (size_t)MDIM * KDIM / 8;                // 512 KB swizzled B

    hipLaunchKernelGGL(quant_both, dim3(256), dim3(256), 0, stream,
                       q, k, (int2*)q8s, (int2*)k8s);
    hipLaunchKernelGGL(gemm_fp8, dim3(1024), dim3(256), 0, stream,
                       (const long*)q8s, (const long*)k8s, C);
}